// Round 4
// baseline (264.500 us; speedup 1.0000x reference)
//
#include <hip/hip_runtime.h>
#include <stdint.h>

#define T_DIM 2048
#define B_DIM 128
#define H_DIM 128
#define QH_DIM 1024
#define NF 32
#define KW 31
#define TT 128               // t's per block in k2
#define NTILE (T_DIM / TT)   // 16
#define CPAD_ROW (T_DIM + 32)

#define NEG_INF (-__builtin_inff())

typedef float v2f __attribute__((ext_vector_type(2)));

__device__ __forceinline__ float fast_tanh(float x) {
    float e = __expf(2.0f * x);
    return 1.0f - 2.0f * __builtin_amdgcn_rcpf(1.0f + e);
}

template <int CTRL>
__device__ __forceinline__ float dpp_add(float x) {
    int m = __builtin_amdgcn_update_dpp(0, __float_as_int(x), CTRL, 0xf, 0xf, true);
    return x + __int_as_float(m);
}
// full 64-lane sum, VALU-only (DPP), result returned wave-uniform (SGPR)
__device__ __forceinline__ float wave_sum64(float x) {
    x = dpp_add<0x111>(x);   // row_shr:1
    x = dpp_add<0x112>(x);   // row_shr:2
    x = dpp_add<0x114>(x);   // row_shr:4
    x = dpp_add<0x118>(x);   // row_shr:8
    x = dpp_add<0x142>(x);   // row_bcast:15
    x = dpp_add<0x143>(x);   // row_bcast:31
    return __int_as_float(__builtin_amdgcn_readlane(__float_as_int(x), 63));
}

// k_prep: padded cum rows [B][T+32] (16 zeros each side) + mask bias rows (0 / -inf).
// Tap/bias reads in k2 become block-uniform s_loads.
__global__ __launch_bounds__(256)
void k_prep(const float* __restrict__ cum, const void* __restrict__ mask,
            float* __restrict__ cpad, float* __restrict__ mbias) {
    const int gid = blockIdx.x * 256 + threadIdx.x;   // grid 1024 -> B*T
    const int b = gid >> 11, t = gid & 2047;
    const int l = threadIdx.x & 63;
    uint32_t u = ((const uint32_t*)mask)[l];
    unsigned long long hi = __ballot(u > 1u);
    unsigned long long nf = __ballot(u != 0u && u != 0x3f800000u);
    int layout = (hi == 0ull) ? 0 : ((nf == 0ull) ? 2 : 1);  // int32 / byte / float
    bool m;
    if (layout == 0)      m = ((const int32_t*)mask)[gid] != 0;
    else if (layout == 1) m = ((const uint8_t*)mask)[gid] != 0;
    else                  m = ((const float*)mask)[gid] != 0.0f;
    mbias[gid] = m ? NEG_INF : 0.0f;
    cpad[b * CPAD_ROW + 16 + t] = cum[gid];
    if (t < 16) cpad[b * CPAD_ROW + t] = 0.0f;
    else if (t >= T_DIM - 16) cpad[b * CPAD_ROW + 32 + t] = 0.0f;
}

// k0: G[k][h] = sum_f Wa[h,f] * conv_w[f,0,k]
__global__ void k0_G(const float* __restrict__ Wa, const float* __restrict__ conv_w,
                     float* __restrict__ G) {
    int gid = blockIdx.x * blockDim.x + threadIdx.x;
    if (gid >= H_DIM * KW) return;
    int k = gid >> 7, h = gid & 127;
    float acc = 0.0f;
    #pragma unroll
    for (int f = 0; f < NF; ++f) acc = fmaf(Wa[h * NF + f], conv_w[f * KW + k], acc);
    G[gid] = acc;
}

// k1: qb[b,h] = query[b,:]·Wq[h,:] + bq[h] + ba[h] + score_b[h] + Wa[h,:]·conv_b
__global__ __launch_bounds__(512)
void k1_query(const float* __restrict__ query, const float* __restrict__ Wq,
              const float* __restrict__ bq, const float* __restrict__ Wa,
              const float* __restrict__ conv_b, const float* __restrict__ ba,
              const float* __restrict__ score_b, float* __restrict__ qb) {
    const int b = blockIdx.x, tid = threadIdx.x;
    const int h = tid & 127, qtr = tid >> 7;
    __shared__ __align__(16) float qrow[QH_DIM];
    __shared__ float partial[512];
    for (int i = tid; i < QH_DIM; i += 512) qrow[i] = query[b * QH_DIM + i];
    __syncthreads();
    const float4* wq4 = (const float4*)(Wq + (size_t)h * QH_DIM + qtr * 256);
    const float4* q4 = (const float4*)(qrow + qtr * 256);
    float acc = 0.0f;
    #pragma unroll 4
    for (int j = 0; j < 64; ++j) {
        float4 w = wq4[j], q = q4[j];
        acc += w.x * q.x + w.y * q.y + w.z * q.z + w.w * q.w;
    }
    if (qtr == 0) {
        float cb = bq[h] + ba[h] + score_b[h];
        #pragma unroll
        for (int f = 0; f < NF; ++f) cb = fmaf(Wa[h * NF + f], conv_b[f], cb);
        acc += cb;
    }
    partial[tid] = acc;
    __syncthreads();
    if (tid < 128) qb[b * H_DIM + h] = partial[h] + partial[h + 128] + partial[h + 256] + partial[h + 384];
}

// k2: fused score + online-softmax + context partials.
// Block: one (b, 128-t tile); wave wv owns 32 t's in 2 chunks of 16; lane owns
// h = {2l, 2l+1}. Taps + mask bias are block-uniform loads (SGPR/K$); score
// reduction is DPP (VALU-only); G read from LDS once per chunk.
__global__ __launch_bounds__(256, 4)
void k2_score(const float* __restrict__ enc, const float* __restrict__ cpad,
              const float* __restrict__ mbias, const float* __restrict__ G,
              const float* __restrict__ qb, const float* __restrict__ score_w,
              float* __restrict__ s_out, float* __restrict__ o_part,
              float* __restrict__ ml_part) {
    const int b = blockIdx.x;           // b fastest: co-dispatched blocks share enc slab
    const int tile = blockIdx.y;
    const int t0 = tile * TT;
    const int tid = threadIdx.x;
    const int l = tid & 63, wv = tid >> 6;

    __shared__ v2f Gs[KW * 64];         // [k][h-pair], 15872 B
    __shared__ float oc[4][H_DIM];
    __shared__ float mwl[4], lwl[4];

    for (int i = tid; i < KW * 64; i += 256) Gs[i] = ((const v2f*)G)[i];
    __syncthreads();

    const v2f base = *(const v2f*)(qb + b * H_DIM + 2 * l);
    const v2f w2 = *(const v2f*)(score_w + 2 * l);
    const float* crow = cpad + b * CPAD_ROW;
    const float* mrow = mbias + b * T_DIM;

    float m_w = NEG_INF, l_w = 0.0f;
    v2f o_w = {0.0f, 0.0f};

    #pragma unroll
    for (int c = 0; c < 2; ++c) {
        const int tb = t0 + wv * 32 + c * 16;

        // block-uniform taps: cum[b][tb+j-15] == cpad[b][tb+j+1]
        float tp[46];
        #pragma unroll
        for (int j = 0; j < 46; ++j) tp[j] = crow[tb + j + 1];

        // enc prefetch (16 independent b64 loads; consumed after FIR)
        const float* ep = enc + ((size_t)tb * B_DIM + b) * H_DIM + 2 * l;
        v2f ee[16];
        #pragma unroll
        for (int it = 0; it < 16; ++it)
            ee[it] = *(const v2f*)(ep + (size_t)it * (B_DIM * H_DIM));

        // FIR: acc[t] = base + sum_k G[k]*tap[t+k]
        v2f acc[16];
        #pragma unroll
        for (int it = 0; it < 16; ++it) acc[it] = base;
        #pragma unroll
        for (int k = 0; k < KW; ++k) {
            const v2f g = Gs[k * 64 + l];
            #pragma unroll
            for (int it = 0; it < 16; ++it) {
                const float cc = tp[k + it];
                acc[it] = __builtin_elementwise_fma(g, (v2f){cc, cc}, acc[it]);
            }
        }

        // scores (wave-uniform after DPP reduce)
        float su[16];
        #pragma unroll
        for (int it = 0; it < 16; ++it) {
            v2f a = acc[it] + ee[it];
            float p = w2.x * fast_tanh(a.x) + w2.y * fast_tanh(a.y);
            su[it] = wave_sum64(p) + mrow[tb + it];
        }

        // raw masked scores: lanes 0..15 write 64B contiguous
        float sv = su[0];
        #pragma unroll
        for (int it = 1; it < 16; ++it) sv = (l == it) ? su[it] : sv;
        if (l < 16) s_out[b * T_DIM + tb + l] = sv;

        // online-softmax fold
        float mc = su[0];
        #pragma unroll
        for (int it = 1; it < 16; ++it) mc = fmaxf(mc, su[it]);
        const float m_new = fmaxf(m_w, mc);
        const float m_use = (m_new == NEG_INF) ? 0.0f : m_new;
        const float alpha = __expf(m_w - m_use);
        float lsum = 0.0f;
        v2f osum = {0.0f, 0.0f};
        #pragma unroll
        for (int it = 0; it < 16; ++it) {
            const float e = __expf(su[it] - m_use);
            lsum += e;
            osum = __builtin_elementwise_fma((v2f){e, e}, ee[it], osum);
        }
        l_w = fmaf(l_w, alpha, lsum);
        o_w = __builtin_elementwise_fma(o_w, (v2f){alpha, alpha}, osum);
        m_w = m_new;
    }

    // combine 4 waves -> per-tile (m, l, o[128])
    oc[wv][2 * l] = o_w.x;
    oc[wv][2 * l + 1] = o_w.y;
    if (l == 0) { mwl[wv] = m_w; lwl[wv] = l_w; }
    __syncthreads();
    if (tid < H_DIM) {
        const float mb = fmaxf(fmaxf(mwl[0], mwl[1]), fmaxf(mwl[2], mwl[3]));
        const float mu = (mb == NEG_INF) ? 0.0f : mb;
        const float b0 = __expf(mwl[0] - mu), b1 = __expf(mwl[1] - mu);
        const float b2 = __expf(mwl[2] - mu), b3 = __expf(mwl[3] - mu);
        const float o = oc[0][tid] * b0 + oc[1][tid] * b1 + oc[2][tid] * b2 + oc[3][tid] * b3;
        const int tbase = b * NTILE + tile;
        o_part[tbase * H_DIM + tid] = o;
        if (tid == 0) {
            ml_part[tbase * 2] = mb;
            ml_part[tbase * 2 + 1] = lwl[0] * b0 + lwl[1] * b1 + lwl[2] * b2 + lwl[3] * b3;
        }
    }
}

// k5: per-b global combine + alignment/cum epilogue
__global__ __launch_bounds__(256)
void k5_final(float* __restrict__ s_align, const float* __restrict__ cum_in,
              float* __restrict__ cum_out, const float* __restrict__ o_part,
              const float* __restrict__ ml_part, float* __restrict__ ctx) {
    const int b = blockIdx.x, tid = threadIdx.x;
    __shared__ float sm[NTILE], sl[NTILE], sb[NTILE];
    if (tid < NTILE) {
        sm[tid] = ml_part[(b * NTILE + tid) * 2];
        sl[tid] = ml_part[(b * NTILE + tid) * 2 + 1];
    }
    __syncthreads();
    float M = sm[0];
    #pragma unroll
    for (int i = 1; i < NTILE; ++i) M = fmaxf(M, sm[i]);
    const float M_use = (M == NEG_INF) ? 0.0f : M;
    if (tid < NTILE) sb[tid] = __expf(sm[tid] - M_use);
    __syncthreads();
    float L = 0.0f;
    #pragma unroll
    for (int i = 0; i < NTILE; ++i) L = fmaf(sl[i], sb[i], L);
    const float invL = 1.0f / L;
    if (tid < H_DIM) {
        float o = 0.0f;
        #pragma unroll
        for (int i = 0; i < NTILE; ++i)
            o = fmaf(o_part[(b * NTILE + i) * H_DIM + tid], sb[i], o);
        ctx[b * H_DIM + tid] = o * invL;
    }
    #pragma unroll
    for (int j = 0; j < 8; ++j) {
        const int idx = b * T_DIM + tid + j * 256;
        const float a = __expf(s_align[idx] - M_use) * invL;
        s_align[idx] = a;
        cum_out[idx] = cum_in[idx] + a;
    }
}

extern "C" void kernel_launch(void* const* d_in, const int* in_sizes, int n_in,
                              void* d_out, int out_size, void* d_ws, size_t ws_size,
                              hipStream_t stream) {
    const float* enc     = (const float*)d_in[0];
    const void*  mask    = d_in[1];
    const float* query   = (const float*)d_in[2];
    const float* cum     = (const float*)d_in[3];
    const float* conv_w  = (const float*)d_in[4];
    const float* conv_b  = (const float*)d_in[5];
    const float* Wq      = (const float*)d_in[6];
    const float* bq      = (const float*)d_in[7];
    const float* Wa      = (const float*)d_in[8];
    const float* ba      = (const float*)d_in[9];
    const float* score_w = (const float*)d_in[10];
    const float* score_b = (const float*)d_in[11];

    float* ctx_out   = (float*)d_out;                    // [B,H]
    float* cum_out   = ctx_out + B_DIM * H_DIM;          // [B,T]
    float* align_out = cum_out + B_DIM * T_DIM;          // [B,T]

    float* G      = (float*)d_ws;                        // [k][h]      4096 (pad)
    float* qb     = G + 4096;                            // [B,H]       16384
    float* o_part = qb + B_DIM * H_DIM;                  // [B,NTILE,H] 262144
    float* ml     = o_part + B_DIM * NTILE * H_DIM;      // [B,NTILE,2] 4096
    float* cpad   = ml + 4096;                           // [B][T+32]   266240
    float* mb     = cpad + B_DIM * CPAD_ROW;             // [B,T]       262144

    k_prep<<<B_DIM * T_DIM / 256, 256, 0, stream>>>(cum, mask, cpad, mb);
    k0_G<<<16, 256, 0, stream>>>(Wa, conv_w, G);
    k1_query<<<B_DIM, 512, 0, stream>>>(query, Wq, bq, Wa, conv_b, ba, score_b, qb);
    k2_score<<<dim3(B_DIM, NTILE), 256, 0, stream>>>(enc, cpad, mb, G, qb, score_w,
                                                     align_out, o_part, ml);
    k5_final<<<B_DIM, 256, 0, stream>>>(align_out, cum, cum_out, o_part, ml, ctx_out);
}